// Round 1
// baseline (107.968 us; speedup 1.0000x reference)
//
#include <hip/hip_runtime.h>
#include <math.h>
#include <limits.h>

// out[b,h,w,c] = vgg[b,h,w,c] - t[b,h,w]
//   t = (a > 0.5f) ? a : 0,  a[b,h,w] = interm[b,h,w, argmax_c logits[b,c]]
// B=256, H=W=7 (P=49 positions), C_in=1000, C_out=512. All fp32.

#define NB     256      // batch
#define NP     49       // 7*7 positions
#define CIN    1000     // interm / logits channels
#define COUT   512      // vgg channels
#define VEC_PER_SAMPLE (NP * COUT / 4)   // 6272 float4 per sample
#define KBLK   4        // blocks per sample

__global__ __launch_bounds__(256) void cam_sub_kernel(
    const float* __restrict__ vgg,
    const float* __restrict__ interm,
    const float* __restrict__ logits,
    float* __restrict__ out)
{
    const int b     = blockIdx.x / KBLK;
    const int chunk = blockIdx.x % KBLK;
    const int tid   = threadIdx.x;

    // ---- per-sample argmax over logits[b, 0..999] (all 256 threads) ----
    const float* lg = logits + b * CIN;
    float bv = -INFINITY;
    int   bi = INT_MAX;
    for (int i = tid; i < CIN; i += 256) {
        float v = lg[i];
        if (v > bv || (v == bv && i < bi)) { bv = v; bi = i; }
    }
    // wave-64 butterfly-down reduce with first-index tie-break
    for (int off = 32; off >= 1; off >>= 1) {
        float ov = __shfl_down(bv, off, 64);
        int   oi = __shfl_down(bi, off, 64);
        if (ov > bv || (ov == bv && oi < bi)) { bv = ov; bi = oi; }
    }
    __shared__ float wv[4];
    __shared__ int   wi[4];
    __shared__ int   s_idx;
    __shared__ float s_a[NP];
    const int wave = tid >> 6;
    if ((tid & 63) == 0) { wv[wave] = bv; wi[wave] = bi; }
    __syncthreads();
    if (tid == 0) {
        float v = wv[0]; int i = wi[0];
        #pragma unroll
        for (int w = 1; w < 4; ++w)
            if (wv[w] > v || (wv[w] == v && wi[w] < i)) { v = wv[w]; i = wi[w]; }
        s_idx = i;
    }
    __syncthreads();
    const int idx = s_idx;

    // ---- gather + threshold the 49 CAM values into LDS ----
    if (tid < NP) {
        float a = interm[((size_t)b * NP + tid) * CIN + idx];
        s_a[tid] = (a > 0.5f) ? a : 0.0f;
    }
    __syncthreads();

    // ---- streaming subtract, float4-vectorized, coalesced ----
    const float4* __restrict__ vgg4 = (const float4*)(vgg + (size_t)b * NP * COUT);
    float4*       __restrict__ out4 = (float4*)(out + (size_t)b * NP * COUT);
    for (int v = chunk * 256 + tid; v < VEC_PER_SAMPLE; v += KBLK * 256) {
        const float a = s_a[v >> 7];   // 512/4 = 128 float4 per position
        float4 x = vgg4[v];
        x.x -= a; x.y -= a; x.z -= a; x.w -= a;
        out4[v] = x;
    }
}

extern "C" void kernel_launch(void* const* d_in, const int* in_sizes, int n_in,
                              void* d_out, int out_size, void* d_ws, size_t ws_size,
                              hipStream_t stream) {
    const float* vgg    = (const float*)d_in[0];  // [256,7,7,512]
    const float* interm = (const float*)d_in[1];  // [256,7,7,1000]
    const float* logits = (const float*)d_in[2];  // [256,1000]
    float* out = (float*)d_out;                   // [256,7,7,512]

    dim3 grid(NB * KBLK);
    dim3 block(256);
    hipLaunchKernelGGL(cam_sub_kernel, grid, block, 0, stream,
                       vgg, interm, logits, out);
}